// Round 12
// baseline (902.715 us; speedup 1.0000x reference)
//
#include <hip/hip_runtime.h>
#include <math.h>

#define BB 128
#define NTOK 197
#define CC 768
#define HH 12
#define HD 64
#define HIDN 3072
#define NP 177
#define NPATCH 196
#define THRK 19
#define MR (BB*NP)   // 22656 real rows
#define MRP 22784    // 89*256 padded for 256-tile GEMM

using short8 = __attribute__((ext_vector_type(8))) short;
using f32x4  = __attribute__((ext_vector_type(4))) float;

__device__ __forceinline__ unsigned short f2b(float f){
  unsigned u = __builtin_bit_cast(unsigned, f);
  u += 0x7fffu + ((u >> 16) & 1u);
  return (unsigned short)(u >> 16);
}

__device__ __forceinline__ float b2f(unsigned short s){
  unsigned u = (unsigned)s << 16;
  return __builtin_bit_cast(float, u);
}

// gelu via A&S 7.1.26 erf (|err|<=1.5e-7); validated R6-R11
__device__ __forceinline__ float fast_gelu(float v){
  float u = v * 0.70710678118654752f;
  float a = fabsf(u);
  float t = 1.0f / fmaf(0.3275911f, a, 1.0f);
  float p = fmaf(1.061405429f, t, -1.453152027f);
  p = fmaf(p, t, 1.421413741f);
  p = fmaf(p, t, -0.284496736f);
  p = fmaf(p, t, 0.254829592f);
  p = p * t;
  float e = __expf(-a*a);
  float erfu = copysignf(1.0f - p*e, u);
  return 0.5f * v * (1.0f + erfu);
}

__device__ __forceinline__ void gload16(const void* src, void* lds){
  __builtin_amdgcn_global_load_lds(
      (const __attribute__((address_space(1))) unsigned int*)src,
      (__attribute__((address_space(3))) unsigned int*)lds,
      16, 0, 0);
}

// ---------- fused transpose+cvt: W[K][N] f32 -> Wt[N][K] bf16 ----------
__global__ void tcvt_kernel(const float* __restrict__ in, unsigned short* __restrict__ out, int K, int N){
  __shared__ float tile[64][65];
  int n0 = blockIdx.x*64, k0 = blockIdx.y*64;
  int t = threadIdx.x;
  int r = t >> 6, c = t & 63;
  #pragma unroll
  for (int i = 0; i < 16; ++i)
    tile[r + i*4][c] = in[(size_t)(k0 + r + i*4)*N + n0 + c];
  __syncthreads();
  #pragma unroll
  for (int i = 0; i < 16; ++i)
    out[(size_t)(n0 + r + i*4)*K + k0 + c] = f2b(tile[c][r + i*4]);
}

// ---------- scoring path (fp64 accum: selection boundary must not flip) ----------
__global__ void q0_kernel(const float* __restrict__ x, const float* __restrict__ Wqkv, float* __restrict__ q0){
  int b = blockIdx.x, t = threadIdx.x;
  int c = blockIdx.y*256 + t;
  __shared__ float xs[CC];
  for (int j = t; j < CC; j += 256) xs[j] = x[(size_t)b*NTOK*CC + j];
  __syncthreads();
  double acc = 0.0;
  for (int j = 0; j < CC; ++j) acc = fma((double)xs[j], (double)Wqkv[(size_t)j*(3*CC) + c], acc);
  q0[b*CC + c] = (float)acc;
}

__global__ void wvec_kernel(const float* __restrict__ Wqkv, const float* __restrict__ q0, float* __restrict__ wv){
  int b = blockIdx.x;
  int j = blockIdx.y*4 + (threadIdx.x >> 6);
  int l = threadIdx.x & 63;
  const float* row = Wqkv + (size_t)j*(3*CC) + CC;  // Wk column block
  const float* qs = q0 + b*CC;
  double acc = 0.0;
  for (int c = l; c < CC; c += 64) acc = fma((double)row[c], (double)qs[c], acc);
  for (int off = 32; off; off >>= 1) acc += __shfl_down(acc, off);
  if (l == 0) wv[b*CC + j] = (float)acc;
}

__global__ void score_kernel(const float* __restrict__ x, const float* __restrict__ wv, float* __restrict__ sc){
  int m = blockIdx.x, b = blockIdx.y, l = threadIdx.x;  // one wave per (b,m)
  const float* xr = x + ((size_t)b*NTOK + 1 + m)*CC;
  const float* wr = wv + b*CC;
  double acc = 0.0;
  for (int c = l; c < CC; c += 64) acc = fma((double)xr[c], (double)wr[c], acc);
  for (int off = 32; off; off >>= 1) acc += __shfl_down(acc, off);
  if (l == 0) sc[b*NPATCH + m] = (float)(acc * (1.0/12.0));
}

// stable rank (== argsort(argsort) with stable ties), keep rank>19, compact in order
__global__ void select_kernel(const float* __restrict__ sc, int* __restrict__ tok){
  int b = blockIdx.x, t = threadIdx.x;
  __shared__ float s[NPATCH];
  __shared__ int kp[NPATCH];
  for (int m = t; m < NPATCH; m += 256) s[m] = sc[b*NPATCH + m];
  __syncthreads();
  for (int m = t; m < NPATCH; m += 256){
    float v = s[m]; int rank = 0;
    for (int j = 0; j < NPATCH; ++j){
      float u = s[j];
      rank += (u < v) || (u == v && j < m);
    }
    kp[m] = (rank > THRK) ? 1 : 0;
  }
  __syncthreads();
  for (int m = t; m < NPATCH; m += 256){
    if (kp[m]){
      int pos = 0;
      for (int j = 0; j < m; ++j) pos += kp[j];
      tok[b*NP + 1 + pos] = m + 1;
    }
  }
  if (t == 0) tok[b*NP] = 0;
}

// ---------- fused gather + scale + LayerNorm1 ----------
__global__ void gln_kernel(const float* __restrict__ x, const int* __restrict__ tok,
                           const float* __restrict__ g, const float* __restrict__ bt,
                           unsigned short* __restrict__ xkb, unsigned short* __restrict__ hout){
  int row = blockIdx.x, t = threadIdx.x;       // row = b*NP + i
  int b = row / NP;
  int src = tok[row];
  const float* xr = x + ((size_t)b*NTOK + src)*CC;
  float v0 = xr[t]*(1.0f/0.9f), v1 = xr[t+256]*(1.0f/0.9f), v2 = xr[t+512]*(1.0f/0.9f);
  float s = v0+v1+v2, ss = v0*v0+v1*v1+v2*v2;
  for (int off = 32; off; off >>= 1){ s += __shfl_down(s, off); ss += __shfl_down(ss, off); }
  __shared__ float red[8];
  int wid = t >> 6, lane = t & 63;
  if (lane == 0){ red[wid] = s; red[4+wid] = ss; }
  __syncthreads();
  if (t == 0){
    float S = red[0]+red[1]+red[2]+red[3], SS = red[4]+red[5]+red[6]+red[7];
    float mean = S * (1.0f/CC);
    float var = SS * (1.0f/CC) - mean*mean;
    red[0] = mean; red[1] = rsqrtf(var + 1e-5f);
  }
  __syncthreads();
  float mean = red[0], rstd = red[1];
  unsigned short* xrow = xkb + (size_t)row*CC;
  unsigned short* orow = hout + (size_t)row*CC;
  xrow[t]     = f2b(v0); xrow[t+256] = f2b(v1); xrow[t+512] = f2b(v2);
  orow[t]     = f2b((v0-mean)*rstd*g[t]     + bt[t]);
  orow[t+256] = f2b((v1-mean)*rstd*g[t+256] + bt[t+256]);
  orow[t+512] = f2b((v2-mean)*rstd*g[t+512] + bt[t+512]);
}

// ---------- LayerNorm: fp32 in -> bf16 out (LN2) ----------
__global__ void ln_kernel(const float* __restrict__ in, const float* __restrict__ g,
                          const float* __restrict__ bt, unsigned short* __restrict__ out){
  int row = blockIdx.x, t = threadIdx.x;
  const float* xr = in + (size_t)row*CC;
  float v0 = xr[t], v1 = xr[t+256], v2 = xr[t+512];
  float s = v0+v1+v2, ss = v0*v0+v1*v1+v2*v2;
  for (int off = 32; off; off >>= 1){ s += __shfl_down(s, off); ss += __shfl_down(ss, off); }
  __shared__ float red[8];
  int wid = t >> 6, lane = t & 63;
  if (lane == 0){ red[wid] = s; red[4+wid] = ss; }
  __syncthreads();
  if (t == 0){
    float S = red[0]+red[1]+red[2]+red[3], SS = red[4]+red[5]+red[6]+red[7];
    float mean = S * (1.0f/CC);
    float var = SS * (1.0f/CC) - mean*mean;
    red[0] = mean; red[1] = rsqrtf(var + 1e-5f);
  }
  __syncthreads();
  float mean = red[0], rstd = red[1];
  unsigned short* orow = out + (size_t)row*CC;
  orow[t]     = f2b((v0-mean)*rstd*g[t]     + bt[t]);
  orow[t+256] = f2b((v1-mean)*rstd*g[t+256] + bt[t+256]);
  orow[t+512] = f2b((v2-mean)*rstd*g[t+512] + bt[t+512]);
}

// ---------- GEMM: 256x256 tile, BK=32, 3-buffer counted-vmcnt (R9 sync) + XOR swizzle ----------
// 8 waves (2M x 4N), per-wave output 128x64: 12 ds_read_b128 per 32 MFMA (-25% LDS/FLOP vs 128²).
// In-wave quadrant pipeline: read frags(q+1) while MFMA(q) runs -> waves drift, no lockstep (R7 fix).
// A [MRP][K], Bt [N][K] bf16 row-major. nt = K/32 divisible by 3. LDS 96 KB -> 1 block/CU.
// EPI: 0 = plain -> bf16 (padded out buf) ; 1 = +bias +res(bf16) -> f32 (row<Mreal) ;
//      2 = +bias, gelu -> bf16 (padded) ; 3 = +bias +res(f32) -> f32 (row<Mreal)
template<int EPI>
__global__ __launch_bounds__(512, 2) void gemm256(
    const unsigned short* __restrict__ A, const unsigned short* __restrict__ Bt,
    const float* __restrict__ bias, const void* __restrict__ res, void* __restrict__ outp,
    int Mreal, int N, int K)
{
  __shared__ __align__(16) short lds[3*16384];   // per buf: A 8192 shorts + B 8192 shorts
  // bijective XCD swizzle (m204)
  int nwg = gridDim.x, o = blockIdx.x;
  int q = nwg >> 3, rr = nwg & 7;
  int xcd = o & 7, seq = o >> 3;
  int wg = (xcd < rr) ? xcd*(q+1) + seq : rr*(q+1) + (xcd - rr)*q + seq;
  int nx = N >> 8;
  int m0 = (wg / nx) << 8, n0 = (wg % nx) << 8;

  int t = threadIdx.x, w = t >> 6, l = t & 63;
  int wr = w >> 2, wc = w & 3;
  f32x4 acc[8][4] = {};
  int nt = K >> 5;

  auto stage = [&](int kti, int sb){
    int kt = kti << 5;
    short* buf = &lds[sb*16384];
    #pragma unroll
    for (int i = 0; i < 2; ++i){            // A rounds
      int idx = i*512 + t;                  // 16B-chunk index in [0,1024)
      int row = idx >> 2, c = idx & 3;
      int cg = c ^ ((row >> 1) & 3);        // inverse-swizzled source chunk
      gload16(A + (size_t)(m0 + row)*K + kt + cg*8, &buf[idx*8]);
    }
    #pragma unroll
    for (int i = 0; i < 2; ++i){            // B rounds
      int idx = i*512 + t;
      int row = idx >> 2, c = idx & 3;
      int cg = c ^ ((row >> 1) & 3);
      gload16(Bt + (size_t)(n0 + row)*K + kt + cg*8, &buf[8192 + idx*8]);
    }
  };
  auto readB = [&](int cb, short8* bfr){
    const short* Bb = &lds[cb*16384 + 8192];
    #pragma unroll
    for (int j = 0; j < 4; ++j){
      int row = wc*64 + j*16 + (l & 15);
      int ck = (l >> 4) ^ ((row >> 1) & 3);
      bfr[j] = *reinterpret_cast<const short8*>(&Bb[row*32 + ck*8]);
    }
  };
  auto readA2 = [&](int cb, int qd, short8* afr){
    const short* Ab = &lds[cb*16384];
    #pragma unroll
    for (int f = 0; f < 2; ++f){
      int row = wr*128 + qd*32 + f*16 + (l & 15);
      int ck = (l >> 4) ^ ((row >> 1) & 3);
      afr[f] = *reinterpret_cast<const short8*>(&Ab[row*32 + ck*8]);
    }
  };
  auto mfma8 = [&](const short8* afr, const short8* bfr, int qd){
    __builtin_amdgcn_s_setprio(1);
    #pragma unroll
    for (int f = 0; f < 2; ++f)
      #pragma unroll
      for (int j = 0; j < 4; ++j)
        acc[qd*2+f][j] = __builtin_amdgcn_mfma_f32_16x16x32_bf16(afr[f], bfr[j], acc[qd*2+f][j], 0, 0, 0);
    __builtin_amdgcn_s_setprio(0);
  };
  auto step = [&](int ti, int cb, int sb){
    bool more = (ti + 2) < nt;
    if (more) stage(ti + 2, sb);
    short8 bfr[4], af0[2], af1[2];
    readB(cb, bfr);
    readA2(cb, 0, af0);
    readA2(cb, 1, af1);  mfma8(af0, bfr, 0);   // read q1 ahead of mfma q0
    readA2(cb, 2, af0);  mfma8(af1, bfr, 1);
    readA2(cb, 3, af1);  mfma8(af0, bfr, 2);
                         mfma8(af1, bfr, 3);
    if (more) asm volatile("s_waitcnt vmcnt(4)" ::: "memory");  // tile ti+1 landed; ti+2 in flight
    else      asm volatile("s_waitcnt vmcnt(0)" ::: "memory");
    __builtin_amdgcn_s_barrier();
    asm volatile("" ::: "memory");
  };

  // prologue: tiles 0,1 in flight; vmcnt(4) confirms tile 0 (tile 1 still flying)
  stage(0, 0); stage(1, 1);
  asm volatile("s_waitcnt vmcnt(4)" ::: "memory");
  __builtin_amdgcn_s_barrier();
  asm volatile("" ::: "memory");

  #pragma unroll 1
  for (int ti = 0; ti < nt; ti += 3){   // nt = 24 or 96
    step(ti,     0, 2);
    step(ti + 1, 1, 0);
    step(ti + 2, 2, 1);
  }

  #pragma unroll
  for (int rf = 0; rf < 8; ++rf){
    int row0 = m0 + wr*128 + rf*16 + (l >> 4)*4;
    #pragma unroll
    for (int j = 0; j < 4; ++j){
      int col = n0 + wc*64 + j*16 + (l & 15);
      #pragma unroll
      for (int r = 0; r < 4; ++r){
        int row = row0 + r;
        float v = acc[rf][j][r];
        if (EPI != 0) v += bias[col];
        if (EPI == 2) v = fast_gelu(v);
        if (EPI == 0 || EPI == 2){
          ((unsigned short*)outp)[(size_t)row*N + col] = f2b(v);   // padded buffer
        } else if (row < Mreal){
          if (EPI == 1) v += b2f(((const unsigned short*)res)[(size_t)row*N + col]);
          else          v += ((const float*)res)[(size_t)row*N + col];
          ((float*)outp)[(size_t)row*N + col] = v;
        }
      }
    }
  }
}

// ---------- fused attention: QK^T -> softmax -> PV, per (rowblock, head, batch) ----------
__global__ __launch_bounds__(256) void attn_kernel(const unsigned short* __restrict__ qkv2,
                                                   unsigned short* __restrict__ o)
{
  int rt = blockIdx.x, h = blockIdx.y, b = blockIdx.z;
  int t = threadIdx.x, w = t >> 6, l = t & 63;
  __shared__ short Vt[64*192];       // Vt[d][m], m padded to 192
  __shared__ short P[4][16*192];     // per-wave P strip
  for (int idx = t; idx < NP*8; idx += 256){
    int m = idx >> 3, d0 = (idx & 7)*8;
    short8 v = *reinterpret_cast<const short8*>(qkv2 + (size_t)(b*NP+m)*(3*CC) + 2*CC + h*HD + d0);
    #pragma unroll
    for (int j = 0; j < 8; ++j) Vt[(d0+j)*192 + m] = v[j];
  }
  for (int idx = t; idx < 64*15; idx += 256){
    int d = idx/15, m = NP + idx%15;
    Vt[d*192 + m] = 0;
  }
  __syncthreads();
  int nb = rt*64 + w*16;
  int g = l >> 4, c = l & 15;
  int nq = nb + c; if (nq > NP-1) nq = NP-1;
  const unsigned short* qrow = qkv2 + (size_t)(b*NP+nq)*(3*CC) + h*HD + 8*g;
  short8 aq0 = *reinterpret_cast<const short8*>(qrow);
  short8 aq1 = *reinterpret_cast<const short8*>(qrow + 32);
  f32x4 acc[12];
  #pragma unroll
  for (int ct = 0; ct < 12; ++ct){
    int m = ct*16 + c; if (m > NP-1) m = NP-1;
    const unsigned short* krow = qkv2 + (size_t)(b*NP+m)*(3*CC) + CC + h*HD + 8*g;
    short8 bk0 = *reinterpret_cast<const short8*>(krow);
    short8 bk1 = *reinterpret_cast<const short8*>(krow + 32);
    f32x4 a = {};
    a = __builtin_amdgcn_mfma_f32_16x16x32_bf16(aq0, bk0, a, 0, 0, 0);
    a = __builtin_amdgcn_mfma_f32_16x16x32_bf16(aq1, bk1, a, 0, 0, 0);
    acc[ct] = a;
  }
  float mx[4] = {-INFINITY, -INFINITY, -INFINITY, -INFINITY};
  #pragma unroll
  for (int ct = 0; ct < 12; ++ct){
    bool valid = (ct*16 + c) < NP;
    #pragma unroll
    for (int r = 0; r < 4; ++r){
      float v = valid ? acc[ct][r]*0.125f : -INFINITY;
      acc[ct][r] = v;
      mx[r] = fmaxf(mx[r], v);
    }
  }
  #pragma unroll
  for (int off = 1; off < 16; off <<= 1){
    #pragma unroll
    for (int r = 0; r < 4; ++r) mx[r] = fmaxf(mx[r], __shfl_xor(mx[r], off));
  }
  float sm2[4] = {0.f, 0.f, 0.f, 0.f};
  #pragma unroll
  for (int ct = 0; ct < 12; ++ct)
    #pragma unroll
    for (int r = 0; r < 4; ++r){
      float e = __expf(acc[ct][r] - mx[r]);
      acc[ct][r] = e; sm2[r] += e;
    }
  #pragma unroll
  for (int off = 1; off < 16; off <<= 1){
    #pragma unroll
    for (int r = 0; r < 4; ++r) sm2[r] += __shfl_xor(sm2[r], off);
  }
  float inv[4];
  #pragma unroll
  for (int r = 0; r < 4; ++r) inv[r] = 1.0f / sm2[r];
  #pragma unroll
  for (int ct = 0; ct < 12; ++ct)
    #pragma unroll
    for (int r = 0; r < 4; ++r)
      P[w][(4*g + r)*192 + ct*16 + c] = (short)f2b(acc[ct][r]*inv[r]);
  f32x4 acc2[4] = {};
  __builtin_amdgcn_s_setprio(1);
  #pragma unroll
  for (int ks = 0; ks < 6; ++ks){
    short8 pa = *reinterpret_cast<const short8*>(&P[w][c*192 + ks*32 + 8*g]);
    #pragma unroll
    for (int ct2 = 0; ct2 < 4; ++ct2){
      short8 bv = *reinterpret_cast<const short8*>(&Vt[(ct2*16 + c)*192 + ks*32 + 8*g]);
      acc2[ct2] = __builtin_amdgcn_mfma_f32_16x16x32_bf16(pa, bv, acc2[ct2], 0, 0, 0);
    }
  }
  __builtin_amdgcn_s_setprio(0);
  #pragma unroll
  for (int ct2 = 0; ct2 < 4; ++ct2){
    #pragma unroll
    for (int r = 0; r < 4; ++r){
      int n = nb + 4*g + r;
      if (n < NP) o[(size_t)(b*NP+n)*CC + h*HD + ct2*16 + c] = f2b(acc2[ct2][r]);
    }
  }
}

extern "C" void kernel_launch(void* const* d_in, const int* in_sizes, int n_in,
                              void* d_out, int out_size, void* d_ws, size_t ws_size,
                              hipStream_t stream) {
  const float* x     = (const float*)d_in[0];
  const float* ln1g  = (const float*)d_in[1];
  const float* ln1b  = (const float*)d_in[2];
  const float* Wqkv  = (const float*)d_in[3];
  const float* Wproj = (const float*)d_in[4];
  const float* bproj = (const float*)d_in[5];
  const float* ln2g  = (const float*)d_in[6];
  const float* ln2b  = (const float*)d_in[7];
  const float* W1    = (const float*)d_in[8];
  const float* b1    = (const float*)d_in[9];
  const float* W2    = (const float*)d_in[10];
  const float* b2    = (const float*)d_in[11];
  float* out = (float*)d_out;

  unsigned char* base = (unsigned char*)d_ws;
  size_t off = 0;
  auto alloc = [&](size_t bytes) -> void* {
    off = (off + 255) & ~(size_t)255;
    void* p = base + off;
    off += bytes;
    return p;
  };
  // Transposed bf16 weights [N][K]
  unsigned short* WqkvT  = (unsigned short*)alloc((size_t)(3*CC)*CC*2);
  unsigned short* WprojT = (unsigned short*)alloc((size_t)CC*CC*2);
  unsigned short* W1T    = (unsigned short*)alloc((size_t)HIDN*CC*2);
  unsigned short* W2T    = (unsigned short*)alloc((size_t)CC*HIDN*2);
  float* q0   = (float*)alloc((size_t)BB*CC*4);
  float* wv   = (float*)alloc((size_t)BB*CC*4);
  float* sc   = (float*)alloc((size_t)BB*NPATCH*4);
  int*   tok  = (int*)alloc((size_t)BB*NP*4);
  unsigned short* hbuf = (unsigned short*)alloc((size_t)MRP*CC*2);   // padded rows for 256-tile A reads
  unsigned short* xkb  = (unsigned short*)alloc((size_t)MRP*CC*2);   // bf16 residual (pad unread)
  unsigned short* qkv2 = (unsigned short*)alloc((size_t)MRP*3*CC*2); // padded
  if (off > ws_size) return;  // clean fail if workspace too small (~190 MB used)

  unsigned short* obuf = hbuf;                 // alias: ln1-out dead when attn writes
  unsigned short* mid  = xkb;                  // alias: xkb+qkv2 padded region == MRP*HIDN*2 exactly
  float* x2 = out;                             // residual stream 2 lives in d_out

  // zero padded hbuf rows once (keeps padded-row garbage finite & deterministic)
  hipMemsetAsync(hbuf + (size_t)MR*CC, 0, (size_t)(MRP-MR)*CC*2, stream);

  // weights: fused transpose + cvt  (in [K][N] f32 -> out [N][K] bf16)
  tcvt_kernel<<<dim3((3*CC)/64, CC/64), 256, 0, stream>>>(Wqkv,  WqkvT,  CC, 3*CC);
  tcvt_kernel<<<dim3(CC/64, CC/64),     256, 0, stream>>>(Wproj, WprojT, CC, CC);
  tcvt_kernel<<<dim3(HIDN/64, CC/64),   256, 0, stream>>>(W1,    W1T,    CC, HIDN);
  tcvt_kernel<<<dim3(CC/64, HIDN/64),   256, 0, stream>>>(W2,    W2T,    HIDN, CC);

  // scoring + selection
  q0_kernel<<<dim3(BB, 3), 256, 0, stream>>>(x, Wqkv, q0);
  wvec_kernel<<<dim3(BB, CC/4), 256, 0, stream>>>(Wqkv, q0, wv);
  score_kernel<<<dim3(NPATCH, BB), 64, 0, stream>>>(x, wv, sc);
  select_kernel<<<BB, 256, 0, stream>>>(sc, tok);

  // fused gather + scale + LN1
  gln_kernel<<<MR, 256, 0, stream>>>(x, tok, ln1g, ln1b, xkb, hbuf);

  // attention block
  gemm256<0><<<(MRP/256)*((3*CC)/256), 512, 0, stream>>>(hbuf, WqkvT, nullptr, nullptr, qkv2, MR, 3*CC, CC);
  attn_kernel<<<dim3(3, HH, BB), 256, 0, stream>>>(qkv2, obuf);
  gemm256<1><<<(MRP/256)*(CC/256), 512, 0, stream>>>(obuf, WprojT, bproj, xkb, x2, MR, CC, CC);

  // MLP block
  ln_kernel<<<MR, 256, 0, stream>>>(x2, ln2g, ln2b, hbuf);
  gemm256<2><<<(MRP/256)*(HIDN/256), 512, 0, stream>>>(hbuf, W1T, b1, nullptr, mid, MR, HIDN, CC);
  gemm256<3><<<(MRP/256)*(CC/256), 512, 0, stream>>>(mid, W2T, b2, x2, out, MR, CC, HIDN);
}

// Round 13
// 717.959 us; speedup vs baseline: 1.2573x; 1.2573x over previous
//
#include <hip/hip_runtime.h>
#include <math.h>

#define BB 128
#define NTOK 197
#define CC 768
#define HH 12
#define HD 64
#define HIDN 3072
#define NP 177
#define NPATCH 196
#define THRK 19
#define MR (BB*NP)   // 22656 rows = 177*128

using short8 = __attribute__((ext_vector_type(8))) short;
using f32x4  = __attribute__((ext_vector_type(4))) float;

__device__ __forceinline__ unsigned short f2b(float f){
  unsigned u = __builtin_bit_cast(unsigned, f);
  u += 0x7fffu + ((u >> 16) & 1u);
  return (unsigned short)(u >> 16);
}

__device__ __forceinline__ float b2f(unsigned short s){
  unsigned u = (unsigned)s << 16;
  return __builtin_bit_cast(float, u);
}

// gelu via A&S 7.1.26 erf (|err|<=1.5e-7); validated R6-R12
__device__ __forceinline__ float fast_gelu(float v){
  float u = v * 0.70710678118654752f;
  float a = fabsf(u);
  float t = 1.0f / fmaf(0.3275911f, a, 1.0f);
  float p = fmaf(1.061405429f, t, -1.453152027f);
  p = fmaf(p, t, 1.421413741f);
  p = fmaf(p, t, -0.284496736f);
  p = fmaf(p, t, 0.254829592f);
  p = p * t;
  float e = __expf(-a*a);
  float erfu = copysignf(1.0f - p*e, u);
  return 0.5f * v * (1.0f + erfu);
}

__device__ __forceinline__ void gload16(const void* src, void* lds){
  __builtin_amdgcn_global_load_lds(
      (const __attribute__((address_space(1))) unsigned int*)src,
      (__attribute__((address_space(3))) unsigned int*)lds,
      16, 0, 0);
}

// ---------- fused transpose+cvt: W[K][N] f32 -> Wt[N][K] bf16 ----------
__global__ void tcvt_kernel(const float* __restrict__ in, unsigned short* __restrict__ out, int K, int N){
  __shared__ float tile[64][65];
  int n0 = blockIdx.x*64, k0 = blockIdx.y*64;
  int t = threadIdx.x;
  int r = t >> 6, c = t & 63;
  #pragma unroll
  for (int i = 0; i < 16; ++i)
    tile[r + i*4][c] = in[(size_t)(k0 + r + i*4)*N + n0 + c];
  __syncthreads();
  #pragma unroll
  for (int i = 0; i < 16; ++i)
    out[(size_t)(n0 + r + i*4)*K + k0 + c] = f2b(tile[c][r + i*4]);
}

// ---------- scoring path (fp64 accum: selection boundary must not flip) ----------
__global__ void q0_kernel(const float* __restrict__ x, const float* __restrict__ Wqkv, float* __restrict__ q0){
  int b = blockIdx.x, t = threadIdx.x;
  int c = blockIdx.y*256 + t;
  __shared__ float xs[CC];
  for (int j = t; j < CC; j += 256) xs[j] = x[(size_t)b*NTOK*CC + j];
  __syncthreads();
  double acc = 0.0;
  for (int j = 0; j < CC; ++j) acc = fma((double)xs[j], (double)Wqkv[(size_t)j*(3*CC) + c], acc);
  q0[b*CC + c] = (float)acc;
}

// wave-per-row, lane-strided (coalesced) reads  [validated R5-R12]
__global__ void wvec_kernel(const float* __restrict__ Wqkv, const float* __restrict__ q0, float* __restrict__ wv){
  int b = blockIdx.x;
  int j = blockIdx.y*4 + (threadIdx.x >> 6);
  int l = threadIdx.x & 63;
  const float* row = Wqkv + (size_t)j*(3*CC) + CC;  // Wk column block
  const float* qs = q0 + b*CC;
  double acc = 0.0;
  for (int c = l; c < CC; c += 64) acc = fma((double)row[c], (double)qs[c], acc);
  for (int off = 32; off; off >>= 1) acc += __shfl_down(acc, off);
  if (l == 0) wv[b*CC + j] = (float)acc;
}

__global__ void score_kernel(const float* __restrict__ x, const float* __restrict__ wv, float* __restrict__ sc){
  int m = blockIdx.x, b = blockIdx.y, l = threadIdx.x;  // one wave per (b,m)
  const float* xr = x + ((size_t)b*NTOK + 1 + m)*CC;
  const float* wr = wv + b*CC;
  double acc = 0.0;
  for (int c = l; c < CC; c += 64) acc = fma((double)xr[c], (double)wr[c], acc);
  for (int off = 32; off; off >>= 1) acc += __shfl_down(acc, off);
  if (l == 0) sc[b*NPATCH + m] = (float)(acc * (1.0/12.0));
}

// stable rank (== argsort(argsort) with stable ties), keep rank>19, compact in order
__global__ void select_kernel(const float* __restrict__ sc, int* __restrict__ tok){
  int b = blockIdx.x, t = threadIdx.x;
  __shared__ float s[NPATCH];
  __shared__ int kp[NPATCH];
  for (int m = t; m < NPATCH; m += 256) s[m] = sc[b*NPATCH + m];
  __syncthreads();
  for (int m = t; m < NPATCH; m += 256){
    float v = s[m]; int rank = 0;
    for (int j = 0; j < NPATCH; ++j){
      float u = s[j];
      rank += (u < v) || (u == v && j < m);
    }
    kp[m] = (rank > THRK) ? 1 : 0;
  }
  __syncthreads();
  for (int m = t; m < NPATCH; m += 256){
    if (kp[m]){
      int pos = 0;
      for (int j = 0; j < m; ++j) pos += kp[j];
      tok[b*NP + 1 + pos] = m + 1;
    }
  }
  if (t == 0) tok[b*NP] = 0;
}

// ---------- fused gather + scale + LayerNorm1 ----------
__global__ void gln_kernel(const float* __restrict__ x, const int* __restrict__ tok,
                           const float* __restrict__ g, const float* __restrict__ bt,
                           unsigned short* __restrict__ xkb, unsigned short* __restrict__ hout){
  int row = blockIdx.x, t = threadIdx.x;       // row = b*NP + i
  int b = row / NP;
  int src = tok[row];
  const float* xr = x + ((size_t)b*NTOK + src)*CC;
  float v0 = xr[t]*(1.0f/0.9f), v1 = xr[t+256]*(1.0f/0.9f), v2 = xr[t+512]*(1.0f/0.9f);
  float s = v0+v1+v2, ss = v0*v0+v1*v1+v2*v2;
  for (int off = 32; off; off >>= 1){ s += __shfl_down(s, off); ss += __shfl_down(ss, off); }
  __shared__ float red[8];
  int wid = t >> 6, lane = t & 63;
  if (lane == 0){ red[wid] = s; red[4+wid] = ss; }
  __syncthreads();
  if (t == 0){
    float S = red[0]+red[1]+red[2]+red[3], SS = red[4]+red[5]+red[6]+red[7];
    float mean = S * (1.0f/CC);
    float var = SS * (1.0f/CC) - mean*mean;
    red[0] = mean; red[1] = rsqrtf(var + 1e-5f);
  }
  __syncthreads();
  float mean = red[0], rstd = red[1];
  unsigned short* xrow = xkb + (size_t)row*CC;
  unsigned short* orow = hout + (size_t)row*CC;
  xrow[t]     = f2b(v0); xrow[t+256] = f2b(v1); xrow[t+512] = f2b(v2);
  orow[t]     = f2b((v0-mean)*rstd*g[t]     + bt[t]);
  orow[t+256] = f2b((v1-mean)*rstd*g[t+256] + bt[t+256]);
  orow[t+512] = f2b((v2-mean)*rstd*g[t+512] + bt[t+512]);
}

// ---------- LayerNorm2: bf16 in -> bf16 out ----------
__global__ void lnb_kernel(const unsigned short* __restrict__ in, const float* __restrict__ g,
                           const float* __restrict__ bt, unsigned short* __restrict__ out){
  int row = blockIdx.x, t = threadIdx.x;
  const unsigned short* xr = in + (size_t)row*CC;
  float v0 = b2f(xr[t]), v1 = b2f(xr[t+256]), v2 = b2f(xr[t+512]);
  float s = v0+v1+v2, ss = v0*v0+v1*v1+v2*v2;
  for (int off = 32; off; off >>= 1){ s += __shfl_down(s, off); ss += __shfl_down(ss, off); }
  __shared__ float red[8];
  int wid = t >> 6, lane = t & 63;
  if (lane == 0){ red[wid] = s; red[4+wid] = ss; }
  __syncthreads();
  if (t == 0){
    float S = red[0]+red[1]+red[2]+red[3], SS = red[4]+red[5]+red[6]+red[7];
    float mean = S * (1.0f/CC);
    float var = SS * (1.0f/CC) - mean*mean;
    red[0] = mean; red[1] = rsqrtf(var + 1e-5f);
  }
  __syncthreads();
  float mean = red[0], rstd = red[1];
  unsigned short* orow = out + (size_t)row*CC;
  orow[t]     = f2b((v0-mean)*rstd*g[t]     + bt[t]);
  orow[t+256] = f2b((v1-mean)*rstd*g[t+256] + bt[t+256]);
  orow[t+512] = f2b((v2-mean)*rstd*g[t+512] + bt[t+512]);
}

// ---------- GEMM: 128x128 tile, BK=32, 3-buffer counted-vmcnt + XOR swizzle (R9/R11-exact) ----------
// A [M][K] bf16 row-major, Bt [N][K] bf16 row-major. M%128==0, N%128==0, nt=K/32 %3==0.
// EPI: 0 = plain -> bf16 ; 1 = +bias +res(bf16) -> bf16 ; 2 = +bias, gelu -> bf16 ;
//      3 = +bias +res(bf16) -> f32
template<int EPI>
__global__ __launch_bounds__(256, 3) void gemm128(
    const unsigned short* __restrict__ A, const unsigned short* __restrict__ Bt,
    const float* __restrict__ bias, const void* __restrict__ res, void* __restrict__ outp,
    int M, int N, int K)
{
  __shared__ __align__(16) short lds[3*8192];   // per buf: A 4096 shorts, B 4096 shorts
  // bijective XCD swizzle (m204)
  int nwg = gridDim.x, o = blockIdx.x;
  int q = nwg >> 3, rr = nwg & 7;
  int xcd = o & 7, seq = o >> 3;
  int wg = (xcd < rr) ? xcd*(q+1) + seq : rr*(q+1) + (xcd - rr)*q + seq;
  int nx = N >> 7;
  int m0 = (wg / nx) << 7, n0 = (wg % nx) << 7;

  int t = threadIdx.x, w = t >> 6, l = t & 63;
  int wr = w >> 1, wc = w & 1;
  f32x4 acc[4][4] = {};
  int nt = K >> 5;

  auto stage = [&](int kti, int sb){
    int kt = kti << 5;
    short* buf = &lds[sb*8192];
    #pragma unroll
    for (int j = 0; j < 2; ++j){
      int row = j*64 + w*16 + (l >> 2);                  // tile row this lane covers
      int gk = ((l & 3) ^ ((row >> 1) & 3)) * 8;         // inverse-swizzled source chunk
      gload16(A  + (size_t)(m0 + row)*K + kt + gk, &buf[(j*64 + w*16)*32]);
      gload16(Bt + (size_t)(n0 + row)*K + kt + gk, &buf[4096 + (j*64 + w*16)*32]);
    }
  };
  auto compute = [&](int cb){
    const short* Ab = &lds[cb*8192];
    const short* Bb = Ab + 4096;
    short8 af[4], bf[4];
    #pragma unroll
    for (int i = 0; i < 4; ++i){
      int Ra = wr*64 + i*16 + (l & 15);
      af[i] = *reinterpret_cast<const short8*>(&Ab[Ra*32 + (((l>>4) ^ ((Ra>>1)&3)))*8]);
      int Rb = wc*64 + i*16 + (l & 15);
      bf[i] = *reinterpret_cast<const short8*>(&Bb[Rb*32 + (((l>>4) ^ ((Rb>>1)&3)))*8]);
    }
    __builtin_amdgcn_s_setprio(1);
    #pragma unroll
    for (int i = 0; i < 4; ++i)
      #pragma unroll
      for (int jn = 0; jn < 4; ++jn)
        acc[i][jn] = __builtin_amdgcn_mfma_f32_16x16x32_bf16(af[i], bf[jn], acc[i][jn], 0, 0, 0);
    __builtin_amdgcn_s_setprio(0);
  };
  auto step = [&](int ti, int cb, int sb){
    bool more = (ti + 2) < nt;
    if (more) stage(ti + 2, sb);
    compute(cb);
    if (more) asm volatile("s_waitcnt vmcnt(4)" ::: "memory");  // next tile landed; next-next in flight
    else      asm volatile("s_waitcnt vmcnt(0)" ::: "memory");
    __builtin_amdgcn_s_barrier();
    asm volatile("" ::: "memory");
  };

  // prologue: tiles 0,1 in flight; vmcnt(4) confirms tile 0, leaves tile 1 flying
  stage(0, 0); stage(1, 1);
  asm volatile("s_waitcnt vmcnt(4)" ::: "memory");
  __builtin_amdgcn_s_barrier();
  asm volatile("" ::: "memory");

  #pragma unroll 1
  for (int ti = 0; ti < nt; ti += 3){   // nt = 24 or 96, divisible by 3
    step(ti,     0, 2);
    step(ti + 1, 1, 0);
    step(ti + 2, 2, 1);
  }

  #pragma unroll
  for (int i = 0; i < 4; ++i)
  #pragma unroll
  for (int jn = 0; jn < 4; ++jn){
    int row = m0 + wr*64 + i*16 + (l>>4)*4;
    int col = n0 + wc*64 + jn*16 + (l&15);
    #pragma unroll
    for (int r = 0; r < 4; ++r){
      float v = acc[i][jn][r];
      if (EPI != 0) v += bias[col];
      if (EPI == 2) v = fast_gelu(v);
      if (EPI == 1 || EPI == 3) v += b2f(((const unsigned short*)res)[(size_t)(row+r)*N + col]);
      if (EPI == 3) ((float*)outp)[(size_t)(row+r)*N + col] = v;
      else          ((unsigned short*)outp)[(size_t)(row+r)*N + col] = f2b(v);
    }
  }
}

// ---------- fused attention: QK^T -> softmax -> PV, per (rowblock, head, batch) ----------
__global__ __launch_bounds__(256) void attn_kernel(const unsigned short* __restrict__ qkv2,
                                                   unsigned short* __restrict__ o)
{
  int rt = blockIdx.x, h = blockIdx.y, b = blockIdx.z;
  int t = threadIdx.x, w = t >> 6, l = t & 63;
  __shared__ short Vt[64*192];       // Vt[d][m], m padded to 192
  __shared__ short P[4][16*192];     // per-wave P strip
  for (int idx = t; idx < NP*8; idx += 256){
    int m = idx >> 3, d0 = (idx & 7)*8;
    short8 v = *reinterpret_cast<const short8*>(qkv2 + (size_t)(b*NP+m)*(3*CC) + 2*CC + h*HD + d0);
    #pragma unroll
    for (int j = 0; j < 8; ++j) Vt[(d0+j)*192 + m] = v[j];
  }
  for (int idx = t; idx < 64*15; idx += 256){
    int d = idx/15, m = NP + idx%15;
    Vt[d*192 + m] = 0;
  }
  __syncthreads();
  int nb = rt*64 + w*16;
  int g = l >> 4, c = l & 15;
  int nq = nb + c; if (nq > NP-1) nq = NP-1;
  const unsigned short* qrow = qkv2 + (size_t)(b*NP+nq)*(3*CC) + h*HD + 8*g;
  short8 aq0 = *reinterpret_cast<const short8*>(qrow);
  short8 aq1 = *reinterpret_cast<const short8*>(qrow + 32);
  f32x4 acc[12];
  #pragma unroll
  for (int ct = 0; ct < 12; ++ct){
    int m = ct*16 + c; if (m > NP-1) m = NP-1;
    const unsigned short* krow = qkv2 + (size_t)(b*NP+m)*(3*CC) + CC + h*HD + 8*g;
    short8 bk0 = *reinterpret_cast<const short8*>(krow);
    short8 bk1 = *reinterpret_cast<const short8*>(krow + 32);
    f32x4 a = {};
    a = __builtin_amdgcn_mfma_f32_16x16x32_bf16(aq0, bk0, a, 0, 0, 0);
    a = __builtin_amdgcn_mfma_f32_16x16x32_bf16(aq1, bk1, a, 0, 0, 0);
    acc[ct] = a;
  }
  float mx[4] = {-INFINITY, -INFINITY, -INFINITY, -INFINITY};
  #pragma unroll
  for (int ct = 0; ct < 12; ++ct){
    bool valid = (ct*16 + c) < NP;
    #pragma unroll
    for (int r = 0; r < 4; ++r){
      float v = valid ? acc[ct][r]*0.125f : -INFINITY;
      acc[ct][r] = v;
      mx[r] = fmaxf(mx[r], v);
    }
  }
  #pragma unroll
  for (int off = 1; off < 16; off <<= 1){
    #pragma unroll
    for (int r = 0; r < 4; ++r) mx[r] = fmaxf(mx[r], __shfl_xor(mx[r], off));
  }
  float sm2[4] = {0.f, 0.f, 0.f, 0.f};
  #pragma unroll
  for (int ct = 0; ct < 12; ++ct)
    #pragma unroll
    for (int r = 0; r < 4; ++r){
      float e = __expf(acc[ct][r] - mx[r]);
      acc[ct][r] = e; sm2[r] += e;
    }
  #pragma unroll
  for (int off = 1; off < 16; off <<= 1){
    #pragma unroll
    for (int r = 0; r < 4; ++r) sm2[r] += __shfl_xor(sm2[r], off);
  }
  float inv[4];
  #pragma unroll
  for (int r = 0; r < 4; ++r) inv[r] = 1.0f / sm2[r];
  #pragma unroll
  for (int ct = 0; ct < 12; ++ct)
    #pragma unroll
    for (int r = 0; r < 4; ++r)
      P[w][(4*g + r)*192 + ct*16 + c] = (short)f2b(acc[ct][r]*inv[r]);
  f32x4 acc2[4] = {};
  __builtin_amdgcn_s_setprio(1);
  #pragma unroll
  for (int ks = 0; ks < 6; ++ks){
    short8 pa = *reinterpret_cast<const short8*>(&P[w][c*192 + ks*32 + 8*g]);
    #pragma unroll
    for (int ct2 = 0; ct2 < 4; ++ct2){
      short8 bv = *reinterpret_cast<const short8*>(&Vt[(ct2*16 + c)*192 + ks*32 + 8*g]);
      acc2[ct2] = __builtin_amdgcn_mfma_f32_16x16x32_bf16(pa, bv, acc2[ct2], 0, 0, 0);
    }
  }
  __builtin_amdgcn_s_setprio(0);
  #pragma unroll
  for (int ct2 = 0; ct2 < 4; ++ct2){
    #pragma unroll
    for (int r = 0; r < 4; ++r){
      int n = nb + 4*g + r;
      if (n < NP) o[(size_t)(b*NP+n)*CC + h*HD + ct2*16 + c] = f2b(acc2[ct2][r]);
    }
  }
}

extern "C" void kernel_launch(void* const* d_in, const int* in_sizes, int n_in,
                              void* d_out, int out_size, void* d_ws, size_t ws_size,
                              hipStream_t stream) {
  const float* x     = (const float*)d_in[0];
  const float* ln1g  = (const float*)d_in[1];
  const float* ln1b  = (const float*)d_in[2];
  const float* Wqkv  = (const float*)d_in[3];
  const float* Wproj = (const float*)d_in[4];
  const float* bproj = (const float*)d_in[5];
  const float* ln2g  = (const float*)d_in[6];
  const float* ln2b  = (const float*)d_in[7];
  const float* W1    = (const float*)d_in[8];
  const float* b1    = (const float*)d_in[9];
  const float* W2    = (const float*)d_in[10];
  const float* b2    = (const float*)d_in[11];
  float* out = (float*)d_out;

  unsigned char* base = (unsigned char*)d_ws;
  size_t off = 0;
  auto alloc = [&](size_t bytes) -> void* {
    off = (off + 255) & ~(size_t)255;
    void* p = base + off;
    off += bytes;
    return p;
  };
  // Transposed bf16 weights [N][K]
  unsigned short* WqkvT  = (unsigned short*)alloc((size_t)(3*CC)*CC*2);
  unsigned short* WprojT = (unsigned short*)alloc((size_t)CC*CC*2);
  unsigned short* W1T    = (unsigned short*)alloc((size_t)HIDN*CC*2);
  unsigned short* W2T    = (unsigned short*)alloc((size_t)CC*HIDN*2);
  float* q0   = (float*)alloc((size_t)BB*CC*4);
  float* wv   = (float*)alloc((size_t)BB*CC*4);
  float* sc   = (float*)alloc((size_t)BB*NPATCH*4);
  int*   tok  = (int*)alloc((size_t)BB*NP*4);
  unsigned short* hbuf = (unsigned short*)alloc((size_t)MR*CC*2);   // ln1-out, then attn-out, then ln2-out
  unsigned short* xkb  = (unsigned short*)alloc((size_t)MR*CC*2);   // bf16 residual 1; dead after gemm<1>
  unsigned short* x2b  = (unsigned short*)alloc((size_t)MR*CC*2);   // bf16 residual 2; live to gemm<3>
  unsigned short* qkv2 = (unsigned short*)alloc((size_t)MR*3*CC*2); // dead after attention
  if (off > ws_size) return;  // clean fail (no fault) if workspace too small (~224 MB)

  unsigned short* obuf = hbuf;                 // alias: ln1-out dead when attn writes
  unsigned short* mid  = xkb;                  // alias: xkb+x2b? NO — mid = xkb..qkv2 span check below
  // mid needs MR*HIDN*2 = 139,198,464 B starting at xkb: covers xkb(34.8M)+x2b(34.8M)+pad... 
  // xkb dead after gemm<1> BUT x2b is NOT dead (gemm<3> res). So mid must skip x2b:
  // use qkv2 (104.4M) + xkb (34.8M) is non-contiguous. Instead: mid = qkv2 start is too small alone
  // (104.4 < 139.2). Solution: mid spans qkv2 + tail? qkv2 is last alloc — no tail.
  // Correct layout: mid aliases [xkb .. xkb+139.2MB) requires x2b NOT in that span.
  // => place x2b AFTER qkv2 instead. Re-derive pointers:
  (void)mid;
  unsigned short* mid2;
  {
    // re-layout: xkb, qkv2 contiguous (mid spans them), x2b after
    // recompute from hbuf end:
    unsigned char* p = (unsigned char*)hbuf + (size_t)MR*CC*2;
    p = (unsigned char*)(((size_t)(p - base) + 255 & ~(size_t)255) + base);
    xkb  = (unsigned short*)p;  p += (size_t)MR*CC*2;
    p = (unsigned char*)(((size_t)(p - base) + 255 & ~(size_t)255) + base);
    qkv2 = (unsigned short*)p;  p += (size_t)MR*3*CC*2;
    p = (unsigned char*)(((size_t)(p - base) + 255 & ~(size_t)255) + base);
    x2b  = (unsigned short*)p;  p += (size_t)MR*CC*2;
    if ((size_t)(p - base) > ws_size) return;
    mid2 = xkb;   // spans xkb+qkv2 = exactly MR*HIDN*2 bytes; both dead when written
  }

  // weights: fused transpose + cvt  (in [K][N] f32 -> out [N][K] bf16)
  tcvt_kernel<<<dim3((3*CC)/64, CC/64), 256, 0, stream>>>(Wqkv,  WqkvT,  CC, 3*CC);
  tcvt_kernel<<<dim3(CC/64, CC/64),     256, 0, stream>>>(Wproj, WprojT, CC, CC);
  tcvt_kernel<<<dim3(HIDN/64, CC/64),   256, 0, stream>>>(W1,    W1T,    CC, HIDN);
  tcvt_kernel<<<dim3(CC/64, HIDN/64),   256, 0, stream>>>(W2,    W2T,    HIDN, CC);

  // scoring + selection
  q0_kernel<<<dim3(BB, 3), 256, 0, stream>>>(x, Wqkv, q0);
  wvec_kernel<<<dim3(BB, CC/4), 256, 0, stream>>>(Wqkv, q0, wv);
  score_kernel<<<dim3(NPATCH, BB), 64, 0, stream>>>(x, wv, sc);
  select_kernel<<<BB, 256, 0, stream>>>(sc, tok);

  // fused gather + scale + LN1
  gln_kernel<<<MR, 256, 0, stream>>>(x, tok, ln1g, ln1b, xkb, hbuf);

  // attention block
  gemm128<0><<<(MR/128)*((3*CC)/128), 256, 0, stream>>>(hbuf, WqkvT, nullptr, nullptr, qkv2, MR, 3*CC, CC);
  attn_kernel<<<dim3(3, HH, BB), 256, 0, stream>>>(qkv2, obuf);
  // x2b = obuf@Wproj + bproj + xkb   (bf16 out)
  gemm128<1><<<(MR/128)*(CC/128), 256, 0, stream>>>(obuf, WprojT, bproj, xkb, x2b, MR, CC, CC);

  // MLP block
  lnb_kernel<<<MR, 256, 0, stream>>>(x2b, ln2g, ln2b, hbuf);
  gemm128<2><<<(MR/128)*(HIDN/128), 256, 0, stream>>>(hbuf, W1T, b1, nullptr, mid2, MR, HIDN, CC);
  gemm128<3><<<(MR/128)*(CC/128), 256, 0, stream>>>(mid2, W2T, b2, x2b, out, MR, CC, HIDN);
}